// Round 6
// baseline (94.786 us; speedup 1.0000x reference)
//
#include <hip/hip_runtime.h>
#include <hip/hip_bf16.h>
#include <math.h>

typedef __attribute__((ext_vector_type(8))) short short8;
typedef __attribute__((ext_vector_type(4))) short short4v;
typedef __attribute__((ext_vector_type(4))) float f32x4;
typedef __attribute__((ext_vector_type(4))) int int4v;

#define XP 1032

__device__ __forceinline__ short f2b(float v) {
  unsigned int u = __builtin_bit_cast(unsigned int, v);
  unsigned int r = (u + 0x7fffu + ((u >> 16) & 1u)) >> 16;
  return (short)(unsigned short)r;
}
__device__ __forceinline__ int ror10(int x, int k) {
  return ((x >> k) | (x << (10 - k))) & 1023;
}
__device__ __forceinline__ int swzj(int j) {
  return j ^ (((j >> 6) & 7) << 3);
}

// ------------------------------------------------------------------
// Kernel 0: convert the four monarch weight tensors fp32 -> bf16.
// ------------------------------------------------------------------
__global__ __launch_bounds__(256) void conv_lr(
    const float* __restrict__ M1L, const float* __restrict__ M1R,
    const float* __restrict__ M2L, const float* __restrict__ M2R,
    short* __restrict__ Lbf)
{
  int g = blockIdx.x * 256 + threadIdx.x;
  const float* srcs[4] = {M1L, M1R, M2L, M2R};
  #pragma unroll
  for (int t = 0; t < 4; ++t) {
    float4 v = *(const float4*)(srcs[t] + (size_t)g * 4);
    short4v o = { f2b(v.x), f2b(v.y), f2b(v.z), f2b(v.w) };
    *(short4v*)(Lbf + (size_t)t * 131072 + (size_t)g * 4) = o;
  }
}

// ------------------------------------------------------------------
// Kernel 1: monarch transform v3 (unchanged from round 5, validated).
// ------------------------------------------------------------------
template<bool USEBF>
__global__ __launch_bounds__(512) void monarch_transform3(
    const float* __restrict__ Q, const float* __restrict__ Kv,
    const float* __restrict__ M1L, const float* __restrict__ M1R,
    const float* __restrict__ M2L, const float* __restrict__ M2R,
    const short* __restrict__ Lbf,
    const float* __restrict__ W, const int* __restrict__ periods,
    short* __restrict__ Qh, short* __restrict__ Kh)
{
  const int bid = blockIdx.x;
  const int xcd = bid & 7;
  const int seq = bid >> 3;
  const int bh  = (xcd << 2) | (seq & 3);
  const int src = (seq >> 2) & 1;
  const int dc  = (seq >> 3) & 3;
  const int b   = bh >> 3;
  const int h   = bh & 7;

  __shared__ short raw[16 * XP];
  __shared__ short scr[16 * XP];

  const int tid  = threadIdx.x;
  const int lane = tid & 63;
  const int w    = tid >> 6;
  const int l15  = lane & 15;
  const int l4   = lane >> 4;

  float ws[4];
  {
    float w0 = W[b*4+0], w1 = W[b*4+1], w2 = W[b*4+2], w3 = W[b*4+3];
    float mx = fmaxf(fmaxf(w0, w1), fmaxf(w2, w3));
    float e0 = expf(w0-mx), e1 = expf(w1-mx), e2 = expf(w2-mx), e3 = expf(w3-mx);
    float inv = 1.0f / (e0+e1+e2+e3);
    ws[0]=e0*inv; ws[1]=e1*inv; ws[2]=e2*inv; ws[3]=e3*inv;
  }

  {
    const int dgrp = tid & 3;
    const int srow = tid >> 2;
    const float* xbase = (src ? Kv : Q)
        + (size_t)b*524288 + h*64 + dc*16 + dgrp*4;
    #pragma unroll
    for (int it = 0; it < 8; ++it) {
      int s = it*128 + srow;
      float4 v = *(const float4*)(xbase + (size_t)s * 512);
      raw[(dgrp*4+0)*XP + s] = f2b(v.x);
      raw[(dgrp*4+1)*XP + s] = f2b(v.y);
      raw[(dgrp*4+2)*XP + s] = f2b(v.z);
      raw[(dgrp*4+3)*XP + s] = f2b(v.w);
    }
  }
  __syncthreads();

  const short* LBs = Lbf + (size_t)(src ? 2 : 0) * 131072;
  const short* RBs = Lbf + (size_t)(src ? 3 : 1) * 131072;
  const float* LF  = src ? M2L : M1L;
  const float* RF  = src ? M2R : M1R;
  short* Out       = src ? Kh : Qh;

  for (int i = 0; i < 4; ++i) {
    const int p    = periods[i];
    const int lp   = 31 - __clz(p);
    const int kin  = 5 + lp;
    const int kf   = 5 - lp;
    const int str  = 1 << (10 - kin);
    const int mask = (1 << kin) - 1;
    const float scale = (src == 0) ? ws[i] : 1.0f;

    f32x4 acc[4][2];
    #pragma unroll
    for (int bi = 0; bi < 4; ++bi)
      #pragma unroll
      for (int rt = 0; rt < 2; ++rt) acc[bi][rt] = (f32x4){0.f,0.f,0.f,0.f};

    #pragma unroll
    for (int bi = 0; bi < 4; ++bi) {
      int bb = w*4 + bi;
      int j0 = bb*32 + l4*8;
      int s0 = (j0 >> kin) | ((j0 & mask) << (10 - kin));
      short8 a;
      #pragma unroll
      for (int e = 0; e < 8; ++e) a[e] = raw[l15*XP + s0 + e*str];
      #pragma unroll
      for (int rt = 0; rt < 2; ++rt) {
        int roff = ((i*32 + bb)*32 + rt*16 + l15)*32 + l4*8;
        short8 bf;
        if (USEBF) {
          bf = *(const short8*)(LBs + roff);
        } else {
          float4 u0 = *(const float4*)(LF + roff);
          float4 u1 = *(const float4*)(LF + roff + 4);
          bf[0]=f2b(u0.x); bf[1]=f2b(u0.y); bf[2]=f2b(u0.z); bf[3]=f2b(u0.w);
          bf[4]=f2b(u1.x); bf[5]=f2b(u1.y); bf[6]=f2b(u1.z); bf[7]=f2b(u1.w);
        }
        acc[bi][rt] = __builtin_amdgcn_mfma_f32_16x16x32_bf16(a, bf, acc[bi][rt], 0, 0, 0);
      }
    }

    #pragma unroll
    for (int rt = 0; rt < 2; ++rt)
      #pragma unroll
      for (int rr = 0; rr < 4; ++rr) {
        short4v v;
        #pragma unroll
        for (int bi = 0; bi < 4; ++bi) v[bi] = f2b(acc[bi][rt][rr]);
        int r  = rt*16 + l15;
        int d  = l4*4 + rr;
        int j2 = r*32 + w*4;
        *(short4v*)&scr[d*XP + swzj(j2)] = v;
      }
    __syncthreads();

    f32x4 ac2[4][2];
    #pragma unroll
    for (int bi = 0; bi < 4; ++bi)
      #pragma unroll
      for (int rt = 0; rt < 2; ++rt) ac2[bi][rt] = (f32x4){0.f,0.f,0.f,0.f};

    #pragma unroll
    for (int bi = 0; bi < 4; ++bi) {
      int bb = w*4 + bi;
      int j0 = bb*32 + l4*8;
      short8 a = *(const short8*)&scr[l15*XP + swzj(j0)];
      #pragma unroll
      for (int rt = 0; rt < 2; ++rt) {
        int roff = ((i*32 + bb)*32 + rt*16 + l15)*32 + l4*8;
        short8 bf;
        if (USEBF) {
          bf = *(const short8*)(RBs + roff);
        } else {
          float4 u0 = *(const float4*)(RF + roff);
          float4 u1 = *(const float4*)(RF + roff + 4);
          bf[0]=f2b(u0.x); bf[1]=f2b(u0.y); bf[2]=f2b(u0.z); bf[3]=f2b(u0.w);
          bf[4]=f2b(u1.x); bf[5]=f2b(u1.y); bf[6]=f2b(u1.z); bf[7]=f2b(u1.w);
        }
        ac2[bi][rt] = __builtin_amdgcn_mfma_f32_16x16x32_bf16(a, bf, ac2[bi][rt], 0, 0, 0);
      }
    }
    __syncthreads();

    #pragma unroll
    for (int bi = 0; bi < 4; ++bi)
      #pragma unroll
      for (int rt = 0; rt < 2; ++rt) {
        int m  = (w*4 + bi)*32 + rt*16 + l15;
        int jo = ror10(m, kf);
        int sw = (jo >> 5) & 3;
        unsigned int lo = (unsigned short)f2b(ac2[bi][rt][0] * scale)
                        | ((unsigned int)(unsigned short)f2b(ac2[bi][rt][1] * scale) << 16);
        unsigned int hi = (unsigned short)f2b(ac2[bi][rt][2] * scale)
                        | ((unsigned int)(unsigned short)f2b(ac2[bi][rt][3] * scale) << 16);
        uint2 pv; pv.x = lo; pv.y = hi;
        *(uint2*)&scr[jo*16 + ((l4 ^ sw) << 2)] = pv;
      }
    __syncthreads();

    {
      size_t obase = ((size_t)bh * 1024) * 256 + i*64 + dc*16;
      #pragma unroll
      for (int it2 = 0; it2 < 2; ++it2) {
        int jo = it2*512 + tid;
        int sw = (jo >> 5) & 3;
        uint2 g[4];
        #pragma unroll
        for (int gg = 0; gg < 4; ++gg)
          g[gg] = *(const uint2*)&scr[jo*16 + ((gg ^ sw) << 2)];
        int4v lo = {(int)g[0].x, (int)g[0].y, (int)g[1].x, (int)g[1].y};
        int4v hi = {(int)g[2].x, (int)g[2].y, (int)g[3].x, (int)g[3].y};
        short* op = Out + obase + (size_t)jo * 256;
        *(int4v*)(op)     = lo;
        *(int4v*)(op + 8) = hi;
      }
    }
    __syncthreads();
  }
}

// ------------------------------------------------------------------
// Kernel 2 v3: stripe GEMM. 256 blocks (8 stripes x 32 bh, XCD-affine:
// bid&7 = bh>>2). Block = 128 rows x 1024 cols of out[bh].
// A (128x256) in VGPRs (loaded once). B as 16 sub-tiles of 64x256,
// double-buffered LDS via global_load_lds with XOR-swizzle
// (inb ^ ((row&15)<<4), same involution on source and ds_read).
// Counted-vmcnt 2-barrier pipeline: vmcnt never drained to 0 in loop.
// Swapped-operand MFMA -> nt float4 stores (4 consecutive l per lane).
// ------------------------------------------------------------------
__global__ __launch_bounds__(256) void score_gemm3(
    const short* __restrict__ Qh, const short* __restrict__ Kh,
    float* __restrict__ Out)
{
  const int bid    = blockIdx.x;
  const int xcd    = bid & 7;
  const int seq    = bid >> 3;
  const int bh     = (xcd << 2) | (seq & 3);
  const int stripe = seq >> 2;             // 0..7
  const int tm     = stripe << 7;

  __shared__ short Bt[2][64 * 256];        // 2 x 32KB

  const int tid  = threadIdx.x;
  const int lane = tid & 63;
  const int w    = tid >> 6;
  const int l15  = lane & 15;
  const int l4   = lane >> 4;

  const short* Qb = Qh + (size_t)bh * (1024*256);
  const short* Kb = Kh + (size_t)bh * (1024*256);
  float* Ob       = Out + ((size_t)bh << 20);

  // ---- A stripe into registers: 2 m-frags x 8 k-chunks ----
  short8 af[2][8];
  #pragma unroll
  for (int m = 0; m < 2; ++m)
    #pragma unroll
    for (int kt = 0; kt < 8; ++kt)
      af[m][kt] = *(const short8*)(Qb + (size_t)(tm + w*32 + m*16 + l15)*256 + kt*32 + l4*8);

  // stage sub-tile `sub` into buffer `buf` (8 x global_load_lds of 16B)
  auto STAGE = [&](int sub, int buf) {
    #pragma unroll
    for (int r = 0; r < 8; ++r) {
      int row = r*8 + (tid >> 5);                       // 0..63
      int inb = ((tid & 31) << 4) ^ ((row & 15) << 4);  // pre-swizzled source
      const short* src = Kb + (size_t)(sub*64 + row)*256 + (inb >> 1);
      __builtin_amdgcn_global_load_lds(
          (const __attribute__((address_space(1))) unsigned int*)src,
          (__attribute__((address_space(3))) unsigned int*)&Bt[buf][(r*4 + w) * 512],
          16, 0, 0);
    }
  };

  // compute sub-tile `sub` from buffer `buf`: 64 MFMA + 8 nt stores
  auto COMPUTE = [&](int sub, int buf) {
    f32x4 acc[2][4];
    #pragma unroll
    for (int m = 0; m < 2; ++m)
      #pragma unroll
      for (int fn = 0; fn < 4; ++fn) acc[m][fn] = (f32x4){0.f,0.f,0.f,0.f};

    const char* Bbase = (const char*)&Bt[buf][0];
    #pragma unroll
    for (int kt = 0; kt < 8; ++kt) {
      short8 bf[4];
      #pragma unroll
      for (int fn = 0; fn < 4; ++fn) {
        int row = fn*16 + l15;
        int byt = (kt*64 + l4*16) ^ (l15 << 4);
        bf[fn] = *(const short8*)(Bbase + row*512 + byt);
      }
      #pragma unroll
      for (int m = 0; m < 2; ++m)
        #pragma unroll
        for (int fn = 0; fn < 4; ++fn)
          acc[m][fn] = __builtin_amdgcn_mfma_f32_16x16x32_bf16(bf[fn], af[m][kt], acc[m][fn], 0, 0, 0);
    }
    #pragma unroll
    for (int m = 0; m < 2; ++m) {
      int srow = tm + w*32 + m*16 + l15;
      #pragma unroll
      for (int fn = 0; fn < 4; ++fn) {
        int lcol = sub*64 + fn*16 + l4*4;
        __builtin_nontemporal_store(acc[m][fn],
            (f32x4*)(Ob + ((size_t)srow << 10) + lcol));
      }
    }
  };

  // ---- pipelined sub-tile loop (counted vmcnt; never drain to 0) ----
  STAGE(0, 0);
  STAGE(1, 1);
  asm volatile("s_waitcnt vmcnt(8)" ::: "memory");   // A(16)+st0(8) done; st1 in flight
  __builtin_amdgcn_sched_barrier(0);
  __builtin_amdgcn_s_barrier();
  COMPUTE(0, 0);

  for (int t = 1; t < 15; ++t) {
    __builtin_amdgcn_s_barrier();                    // WAR: all done reading buf[(t+1)&1]
    STAGE(t + 1, (t + 1) & 1);
    asm volatile("s_waitcnt vmcnt(16)" ::: "memory"); // stage(t) done; stores(t-1)+stage(t+1) in flight
    __builtin_amdgcn_sched_barrier(0);
    __builtin_amdgcn_s_barrier();
    COMPUTE(t, t & 1);
  }

  __builtin_amdgcn_s_barrier();
  asm volatile("s_waitcnt vmcnt(8)" ::: "memory");   // stage(15) done; stores(14) may linger
  __builtin_amdgcn_sched_barrier(0);
  __builtin_amdgcn_s_barrier();
  COMPUTE(15, 1);
}

extern "C" void kernel_launch(void* const* d_in, const int* in_sizes, int n_in,
                              void* d_out, int out_size, void* d_ws, size_t ws_size,
                              hipStream_t stream) {
  const float* Q   = (const float*)d_in[0];
  const float* Kv  = (const float*)d_in[1];
  const float* M1L = (const float*)d_in[2];
  const float* M1R = (const float*)d_in[3];
  const float* M2L = (const float*)d_in[4];
  const float* M2R = (const float*)d_in[5];
  const float* W   = (const float*)d_in[6];
  const int* per   = (const int*)d_in[7];
  float* Out       = (float*)d_out;

  const size_t qsz = (size_t)32 * 1024 * 256;
  short* Qhat = (short*)d_ws;
  short* Khat = Qhat + qsz;
  short* Lbf  = Khat + qsz;
  const size_t need = (qsz * 2 + (size_t)4 * 131072) * sizeof(short);
  const bool usebf = (ws_size >= need);

  if (usebf) {
    conv_lr<<<dim3(128), dim3(256), 0, stream>>>(M1L, M1R, M2L, M2R, Lbf);
    monarch_transform3<true><<<dim3(256), dim3(512), 0, stream>>>(
        Q, Kv, M1L, M1R, M2L, M2R, Lbf, W, per, Qhat, Khat);
  } else {
    monarch_transform3<false><<<dim3(256), dim3(512), 0, stream>>>(
        Q, Kv, M1L, M1R, M2L, M2R, Lbf, W, per, Qhat, Khat);
  }

  score_gemm3<<<dim3(256), dim3(256), 0, stream>>>(Qhat, Khat, Out);
}

// Round 7
// 83.928 us; speedup vs baseline: 1.1294x; 1.1294x over previous
//
#include <hip/hip_runtime.h>
#include <hip/hip_bf16.h>
#include <math.h>

typedef __attribute__((ext_vector_type(8))) short short8;
typedef __attribute__((ext_vector_type(4))) short short4v;
typedef __attribute__((ext_vector_type(4))) float f32x4;
typedef __attribute__((ext_vector_type(4))) int int4v;

#define XP 1032

__device__ __forceinline__ short f2b(float v) {
  unsigned int u = __builtin_bit_cast(unsigned int, v);
  unsigned int r = (u + 0x7fffu + ((u >> 16) & 1u)) >> 16;
  return (short)(unsigned short)r;
}
__device__ __forceinline__ int ror10(int x, int k) {
  return ((x >> k) | (x << (10 - k))) & 1023;
}
__device__ __forceinline__ int swzj(int j) {
  return j ^ (((j >> 6) & 7) << 3);
}

// ------------------------------------------------------------------
// Kernel 0: convert the four monarch weight tensors fp32 -> bf16.
// Lbf layout: [slot][131072], slot = {M1L, M1R, M2L, M2R}.
// ------------------------------------------------------------------
__global__ __launch_bounds__(256) void conv_lr(
    const float* __restrict__ M1L, const float* __restrict__ M1R,
    const float* __restrict__ M2L, const float* __restrict__ M2R,
    short* __restrict__ Lbf)
{
  int g = blockIdx.x * 256 + threadIdx.x;
  const float* srcs[4] = {M1L, M1R, M2L, M2R};
  #pragma unroll
  for (int t = 0; t < 4; ++t) {
    float4 v = *(const float4*)(srcs[t] + (size_t)g * 4);
    short4v o = { f2b(v.x), f2b(v.y), f2b(v.z), f2b(v.w) };
    *(short4v*)(Lbf + (size_t)t * 131072 + (size_t)g * 4) = o;
  }
}

// ------------------------------------------------------------------
// Kernel T1: stage 1 as independent streaming MFMA units.
// bid = g*8 + si, si = src*4+i (XCD-affine per (src,i) slice).
// g = bb1*4 + mgroup. 256 thr = 4 waves; wave handles 8 m-tiles.
// Per unit: A[m=16][c=32] gathered from X (s = s0 + c*str),
// B = L[i][bb1] fragment (VGPR-resident), out -> T3[j1][m] bf16.
// No __syncthreads anywhere (per-wave LDS micro-transpose only).
// ------------------------------------------------------------------
__global__ __launch_bounds__(256) void stage1_k(
    const float* __restrict__ Q, const float* __restrict__ Kv,
    const short* __restrict__ Lbf, const int* __restrict__ periods,
    short* __restrict__ T3)
{
  const int bid = blockIdx.x;
  const int si  = bid & 7;
  const int src = si >> 2;
  const int i   = si & 3;
  const int g   = bid >> 3;
  const int bb  = g >> 2;          // 0..31
  const int mg  = g & 3;           // m-group (= b index)

  const int tid  = threadIdx.x;
  const int lane = tid & 63;
  const int w    = tid >> 6;
  const int l15  = lane & 15;
  const int l4   = lane >> 4;

  const int p   = periods[i];
  const int lp  = 31 - __clz(p);
  const int kin = 5 + lp;
  const int str = 1 << (10 - kin);
  const int klo = kin - 5;
  const int s0  = (bb >> klo) | ((bb & ((1 << klo) - 1)) << (15 - kin));

  const float* X  = src ? Kv : Q;
  const short* LB = Lbf + (size_t)(src ? 2 : 0) * 131072;

  short8 wb0 = *(const short8*)(LB + (size_t)((i*32 + bb)*32 + l15)*32 + l4*8);
  short8 wb1 = *(const short8*)(LB + (size_t)((i*32 + bb)*32 + 16 + l15)*32 + l4*8);

  __shared__ short lds[4][2][512];

  short* T3r = T3 + (size_t)(si*1024 + bb*32) * 2048;

  #pragma unroll
  for (int u = 0; u < 8; ++u) {
    int mt  = mg*32 + w*8 + u;       // global m-tile 0..127
    int bh  = mt >> 2;
    int dlo = (mt & 3) << 4;
    const float* xb = X + (size_t)(bh >> 3)*524288 + (bh & 7)*64 + dlo + l15;
    short8 a;
    #pragma unroll
    for (int e = 0; e < 8; ++e) {
      int s = s0 + (l4*8 + e)*str;
      a[e] = f2b(xb[(size_t)s * 512]);
    }
    f32x4 a0 = {0.f,0.f,0.f,0.f}, a1 = {0.f,0.f,0.f,0.f};
    a0 = __builtin_amdgcn_mfma_f32_16x16x32_bf16(a, wb0, a0, 0, 0, 0);
    a1 = __builtin_amdgcn_mfma_f32_16x16x32_bf16(a, wb1, a1, 0, 0, 0);

    short* B = &lds[w][u & 1][0];
    short4v v0 = { f2b(a0[0]), f2b(a0[1]), f2b(a0[2]), f2b(a0[3]) };
    short4v v1 = { f2b(a1[0]), f2b(a1[1]), f2b(a1[2]), f2b(a1[3]) };
    *(short4v*)&B[l15*16 + l4*4]        = v0;   // row r1 = l15,    cols m-local
    *(short4v*)&B[(16 + l15)*16 + l4*4] = v1;   // row r1 = 16+l15
    short8 o = *(const short8*)&B[(lane >> 1)*16 + (lane & 1)*8];
    *(short8*)(T3r + (size_t)(lane >> 1)*2048 + mt*16 + (lane & 1)*8) = o;
  }
}

// ------------------------------------------------------------------
// Kernel T2: stage 2 + output permutation + softmax-weight fold.
// t4[bb2*32+c2] = t3[c2*32+bb2]  (swap32 absorbed into the gather).
// Epilogue: j2 = bb2*32 + r2 -> jo = ror10(j2, kf); 16B stores into
// Qhat/Khat [bh][jo][kd=i*64+d].
// ------------------------------------------------------------------
__global__ __launch_bounds__(256) void stage2_k(
    const short* __restrict__ T3, const short* __restrict__ Lbf,
    const float* __restrict__ W, const int* __restrict__ periods,
    short* __restrict__ Qh, short* __restrict__ Kh)
{
  const int bid = blockIdx.x;
  const int si  = bid & 7;
  const int src = si >> 2;
  const int i   = si & 3;
  const int g   = bid >> 3;
  const int bb  = g >> 2;
  const int mg  = g & 3;

  const int tid  = threadIdx.x;
  const int lane = tid & 63;
  const int w    = tid >> 6;
  const int l15  = lane & 15;
  const int l4   = lane >> 4;

  const int p  = periods[i];
  const int lp = 31 - __clz(p);
  const int kf = 5 - lp;

  const short* RB = Lbf + (size_t)(src ? 3 : 1) * 131072;

  short8 wb0 = *(const short8*)(RB + (size_t)((i*32 + bb)*32 + l15)*32 + l4*8);
  short8 wb1 = *(const short8*)(RB + (size_t)((i*32 + bb)*32 + 16 + l15)*32 + l4*8);

  float scale = 1.0f;
  if (src == 0) {
    const int b = mg;                     // m-group == batch index
    float w0 = W[b*4+0], w1 = W[b*4+1], w2 = W[b*4+2], w3 = W[b*4+3];
    float mx = fmaxf(fmaxf(w0, w1), fmaxf(w2, w3));
    float e0 = expf(w0-mx), e1 = expf(w1-mx), e2 = expf(w2-mx), e3 = expf(w3-mx);
    float inv = 1.0f / (e0+e1+e2+e3);
    float e[4] = {e0, e1, e2, e3};
    scale = e[i] * inv;
  }

  const short* Tb = T3 + (size_t)(si*1024) * 2048;
  short* Out      = src ? Kh : Qh;

  __shared__ short lds[4][2][512];

  #pragma unroll
  for (int u = 0; u < 8; ++u) {
    int mt  = mg*32 + w*8 + u;
    int bh  = mt >> 2;
    int dlo = (mt & 3) << 4;
    const short* tb = Tb + (size_t)mt*16 + l15;
    short8 a;
    #pragma unroll
    for (int e = 0; e < 8; ++e) {
      int j1 = (l4*8 + e)*32 + bb;       // t3 index feeding t4[bb*32 + c2]
      a[e] = tb[(size_t)j1 * 2048];
    }
    f32x4 a0 = {0.f,0.f,0.f,0.f}, a1 = {0.f,0.f,0.f,0.f};
    a0 = __builtin_amdgcn_mfma_f32_16x16x32_bf16(a, wb0, a0, 0, 0, 0);
    a1 = __builtin_amdgcn_mfma_f32_16x16x32_bf16(a, wb1, a1, 0, 0, 0);

    short* B = &lds[w][u & 1][0];
    short4v v0 = { f2b(a0[0]*scale), f2b(a0[1]*scale), f2b(a0[2]*scale), f2b(a0[3]*scale) };
    short4v v1 = { f2b(a1[0]*scale), f2b(a1[1]*scale), f2b(a1[2]*scale), f2b(a1[3]*scale) };
    *(short4v*)&B[l15*16 + l4*4]        = v0;
    *(short4v*)&B[(16 + l15)*16 + l4*4] = v1;
    short8 o = *(const short8*)&B[(lane >> 1)*16 + (lane & 1)*8];

    int r2 = lane >> 1;
    int jo = ror10(bb*32 + r2, kf);
    *(short8*)(Out + (size_t)bh*262144 + (size_t)jo*256 + i*64 + dlo + (lane & 1)*8) = o;
  }
}

// ------------------------------------------------------------------
// Fallback transform (round-5, validated) for small workspaces.
// ------------------------------------------------------------------
template<bool USEBF>
__global__ __launch_bounds__(512) void monarch_transform3(
    const float* __restrict__ Q, const float* __restrict__ Kv,
    const float* __restrict__ M1L, const float* __restrict__ M1R,
    const float* __restrict__ M2L, const float* __restrict__ M2R,
    const short* __restrict__ Lbf,
    const float* __restrict__ W, const int* __restrict__ periods,
    short* __restrict__ Qh, short* __restrict__ Kh)
{
  const int bid = blockIdx.x;
  const int xcd = bid & 7;
  const int seq = bid >> 3;
  const int bh  = (xcd << 2) | (seq & 3);
  const int src = (seq >> 2) & 1;
  const int dc  = (seq >> 3) & 3;
  const int b   = bh >> 3;
  const int h   = bh & 7;

  __shared__ short raw[16 * XP];
  __shared__ short scr[16 * XP];

  const int tid  = threadIdx.x;
  const int lane = tid & 63;
  const int w    = tid >> 6;
  const int l15  = lane & 15;
  const int l4   = lane >> 4;

  float ws[4];
  {
    float w0 = W[b*4+0], w1 = W[b*4+1], w2 = W[b*4+2], w3 = W[b*4+3];
    float mx = fmaxf(fmaxf(w0, w1), fmaxf(w2, w3));
    float e0 = expf(w0-mx), e1 = expf(w1-mx), e2 = expf(w2-mx), e3 = expf(w3-mx);
    float inv = 1.0f / (e0+e1+e2+e3);
    ws[0]=e0*inv; ws[1]=e1*inv; ws[2]=e2*inv; ws[3]=e3*inv;
  }

  {
    const int dgrp = tid & 3;
    const int srow = tid >> 2;
    const float* xbase = (src ? Kv : Q)
        + (size_t)b*524288 + h*64 + dc*16 + dgrp*4;
    #pragma unroll
    for (int it = 0; it < 8; ++it) {
      int s = it*128 + srow;
      float4 v = *(const float4*)(xbase + (size_t)s * 512);
      raw[(dgrp*4+0)*XP + s] = f2b(v.x);
      raw[(dgrp*4+1)*XP + s] = f2b(v.y);
      raw[(dgrp*4+2)*XP + s] = f2b(v.z);
      raw[(dgrp*4+3)*XP + s] = f2b(v.w);
    }
  }
  __syncthreads();

  const short* LBs = Lbf + (size_t)(src ? 2 : 0) * 131072;
  const short* RBs = Lbf + (size_t)(src ? 3 : 1) * 131072;
  const float* LF  = src ? M2L : M1L;
  const float* RF  = src ? M2R : M1R;
  short* Out       = src ? Kh : Qh;

  for (int i = 0; i < 4; ++i) {
    const int p    = periods[i];
    const int lp   = 31 - __clz(p);
    const int kin  = 5 + lp;
    const int kf   = 5 - lp;
    const int str  = 1 << (10 - kin);
    const int mask = (1 << kin) - 1;
    const float scale = (src == 0) ? ws[i] : 1.0f;

    f32x4 acc[4][2];
    #pragma unroll
    for (int bi = 0; bi < 4; ++bi)
      #pragma unroll
      for (int rt = 0; rt < 2; ++rt) acc[bi][rt] = (f32x4){0.f,0.f,0.f,0.f};

    #pragma unroll
    for (int bi = 0; bi < 4; ++bi) {
      int bb = w*4 + bi;
      int j0 = bb*32 + l4*8;
      int s0 = (j0 >> kin) | ((j0 & mask) << (10 - kin));
      short8 a;
      #pragma unroll
      for (int e = 0; e < 8; ++e) a[e] = raw[l15*XP + s0 + e*str];
      #pragma unroll
      for (int rt = 0; rt < 2; ++rt) {
        int roff = ((i*32 + bb)*32 + rt*16 + l15)*32 + l4*8;
        short8 bf;
        if (USEBF) {
          bf = *(const short8*)(LBs + roff);
        } else {
          float4 u0 = *(const float4*)(LF + roff);
          float4 u1 = *(const float4*)(LF + roff + 4);
          bf[0]=f2b(u0.x); bf[1]=f2b(u0.y); bf[2]=f2b(u0.z); bf[3]=f2b(u0.w);
          bf[4]=f2b(u1.x); bf[5]=f2b(u1.y); bf[6]=f2b(u1.z); bf[7]=f2b(u1.w);
        }
        acc[bi][rt] = __builtin_amdgcn_mfma_f32_16x16x32_bf16(a, bf, acc[bi][rt], 0, 0, 0);
      }
    }

    #pragma unroll
    for (int rt = 0; rt < 2; ++rt)
      #pragma unroll
      for (int rr = 0; rr < 4; ++rr) {
        short4v v;
        #pragma unroll
        for (int bi = 0; bi < 4; ++bi) v[bi] = f2b(acc[bi][rt][rr]);
        int r  = rt*16 + l15;
        int d  = l4*4 + rr;
        int j2 = r*32 + w*4;
        *(short4v*)&scr[d*XP + swzj(j2)] = v;
      }
    __syncthreads();

    f32x4 ac2[4][2];
    #pragma unroll
    for (int bi = 0; bi < 4; ++bi)
      #pragma unroll
      for (int rt = 0; rt < 2; ++rt) ac2[bi][rt] = (f32x4){0.f,0.f,0.f,0.f};

    #pragma unroll
    for (int bi = 0; bi < 4; ++bi) {
      int bb = w*4 + bi;
      int j0 = bb*32 + l4*8;
      short8 a = *(const short8*)&scr[l15*XP + swzj(j0)];
      #pragma unroll
      for (int rt = 0; rt < 2; ++rt) {
        int roff = ((i*32 + bb)*32 + rt*16 + l15)*32 + l4*8;
        short8 bf;
        if (USEBF) {
          bf = *(const short8*)(RBs + roff);
        } else {
          float4 u0 = *(const float4*)(RF + roff);
          float4 u1 = *(const float4*)(RF + roff + 4);
          bf[0]=f2b(u0.x); bf[1]=f2b(u0.y); bf[2]=f2b(u0.z); bf[3]=f2b(u0.w);
          bf[4]=f2b(u1.x); bf[5]=f2b(u1.y); bf[6]=f2b(u1.z); bf[7]=f2b(u1.w);
        }
        ac2[bi][rt] = __builtin_amdgcn_mfma_f32_16x16x32_bf16(a, bf, ac2[bi][rt], 0, 0, 0);
      }
    }
    __syncthreads();

    #pragma unroll
    for (int bi = 0; bi < 4; ++bi)
      #pragma unroll
      for (int rt = 0; rt < 2; ++rt) {
        int m  = (w*4 + bi)*32 + rt*16 + l15;
        int jo = ror10(m, kf);
        int sw = (jo >> 5) & 3;
        unsigned int lo = (unsigned short)f2b(ac2[bi][rt][0] * scale)
                        | ((unsigned int)(unsigned short)f2b(ac2[bi][rt][1] * scale) << 16);
        unsigned int hi = (unsigned short)f2b(ac2[bi][rt][2] * scale)
                        | ((unsigned int)(unsigned short)f2b(ac2[bi][rt][3] * scale) << 16);
        uint2 pv; pv.x = lo; pv.y = hi;
        *(uint2*)&scr[jo*16 + ((l4 ^ sw) << 2)] = pv;
      }
    __syncthreads();

    {
      size_t obase = ((size_t)bh * 1024) * 256 + i*64 + dc*16;
      #pragma unroll
      for (int it2 = 0; it2 < 2; ++it2) {
        int jo = it2*512 + tid;
        int sw = (jo >> 5) & 3;
        uint2 gg2[4];
        #pragma unroll
        for (int gg = 0; gg < 4; ++gg)
          gg2[gg] = *(const uint2*)&scr[jo*16 + ((gg ^ sw) << 2)];
        int4v lo = {(int)gg2[0].x, (int)gg2[0].y, (int)gg2[1].x, (int)gg2[1].y};
        int4v hi = {(int)gg2[2].x, (int)gg2[2].y, (int)gg2[3].x, (int)gg2[3].y};
        short* op = Out + obase + (size_t)jo * 256;
        *(int4v*)(op)     = lo;
        *(int4v*)(op + 8) = hi;
      }
    }
    __syncthreads();
  }
}

// ------------------------------------------------------------------
// Kernel 2 (round-3 form, validated ~12us): batched GEMM
// out[s,l] = sum_k Q[s,k]K[l,k], K=256, 128x128 tiles, XCD-affine.
// ------------------------------------------------------------------
__global__ __launch_bounds__(256) void score_gemm(
    const short* __restrict__ Qh, const short* __restrict__ Kh,
    float* __restrict__ Out)
{
  const int bid  = blockIdx.x;
  const int xcd  = bid & 7;
  const int seq  = bid >> 3;
  const int bh   = (xcd << 2) | (seq & 3);
  const int tile = seq >> 2;
  const int tm   = (tile >> 3) << 7;
  const int tn   = (tile & 7) << 7;

  __shared__ short As[128*64];
  __shared__ short Bs[128*64];

  const int tid  = threadIdx.x;
  const int lane = tid & 63;
  const int w    = tid >> 6;
  const int wm   = (w >> 1) << 6;
  const int wn   = (w & 1) << 6;
  const int l15  = lane & 15;
  const int l4   = lane >> 4;

  const short* Qb = Qh + (size_t)bh * (1024*256);
  const short* Kb = Kh + (size_t)bh * (1024*256);

  const int lrow = lane >> 3;
  const int kch  = (((lane & 7) ^ lrow) << 3);

  f32x4 acc[4][4];
  #pragma unroll
  for (int fm = 0; fm < 4; ++fm)
    #pragma unroll
    for (int fn = 0; fn < 4; ++fn) acc[fm][fn] = (f32x4){0.f,0.f,0.f,0.f};

  for (int kt = 0; kt < 4; ++kt) {
    #pragma unroll
    for (int q0 = 0; q0 < 4; ++q0) {
      int seg = w*4 + q0;
      int row = seg*8 + lrow;
      const short* srcA = Qb + (size_t)(tm + row)*256 + kt*64 + kch;
      const short* srcB = Kb + (size_t)(tn + row)*256 + kt*64 + kch;
      __builtin_amdgcn_global_load_lds(
          (const __attribute__((address_space(1))) unsigned int*)srcA,
          (__attribute__((address_space(3))) unsigned int*)&As[seg*512], 16, 0, 0);
      __builtin_amdgcn_global_load_lds(
          (const __attribute__((address_space(1))) unsigned int*)srcB,
          (__attribute__((address_space(3))) unsigned int*)&Bs[seg*512], 16, 0, 0);
    }
    __syncthreads();

    #pragma unroll
    for (int kk = 0; kk < 2; ++kk) {
      short8 af[4], bf[4];
      #pragma unroll
      for (int fm = 0; fm < 4; ++fm) {
        int row = wm + fm*16 + l15;
        int kl  = kk*32 + l4*8;
        af[fm] = *(const short8*)&As[row*64 + (kl ^ ((row & 7) << 3))];
      }
      #pragma unroll
      for (int fn = 0; fn < 4; ++fn) {
        int row = wn + fn*16 + l15;
        int kl  = kk*32 + l4*8;
        bf[fn] = *(const short8*)&Bs[row*64 + (kl ^ ((row & 7) << 3))];
      }
      #pragma unroll
      for (int fm = 0; fm < 4; ++fm)
        #pragma unroll
        for (int fn = 0; fn < 4; ++fn)
          acc[fm][fn] = __builtin_amdgcn_mfma_f32_16x16x32_bf16(bf[fn], af[fm], acc[fm][fn], 0, 0, 0);
    }
    __syncthreads();
  }

  float* Ob = Out + ((size_t)bh << 20);
  #pragma unroll
  for (int fm = 0; fm < 4; ++fm) {
    int srow = tm + wm + fm*16 + l15;
    #pragma unroll
    for (int fn = 0; fn < 4; ++fn) {
      int lcol = tn + wn + fn*16 + l4*4;
      __builtin_nontemporal_store(acc[fm][fn],
          (f32x4*)(Ob + ((size_t)srow << 10) + lcol));
    }
  }
}

extern "C" void kernel_launch(void* const* d_in, const int* in_sizes, int n_in,
                              void* d_out, int out_size, void* d_ws, size_t ws_size,
                              hipStream_t stream) {
  const float* Q   = (const float*)d_in[0];
  const float* Kv  = (const float*)d_in[1];
  const float* M1L = (const float*)d_in[2];
  const float* M1R = (const float*)d_in[3];
  const float* M2L = (const float*)d_in[4];
  const float* M2R = (const float*)d_in[5];
  const float* W   = (const float*)d_in[6];
  const int* per   = (const int*)d_in[7];
  float* Out       = (float*)d_out;

  const size_t qsz = (size_t)32 * 1024 * 256;      // 8388608 shorts each
  short* Qhat = (short*)d_ws;
  short* Khat = Qhat + qsz;
  short* Lbf  = Khat + qsz;                        // 524288 shorts
  short* T3   = Lbf + (size_t)524288;              // 16777216 shorts

  const size_t need_old = (qsz*2 + (size_t)524288) * sizeof(short);
  const size_t need_new = need_old + (size_t)16777216 * sizeof(short);

  if (ws_size >= need_new) {
    conv_lr<<<dim3(128), dim3(256), 0, stream>>>(M1L, M1R, M2L, M2R, Lbf);
    stage1_k<<<dim3(1024), dim3(256), 0, stream>>>(Q, Kv, Lbf, per, T3);
    stage2_k<<<dim3(1024), dim3(256), 0, stream>>>(T3, Lbf, W, per, Qhat, Khat);
  } else if (ws_size >= need_old) {
    conv_lr<<<dim3(128), dim3(256), 0, stream>>>(M1L, M1R, M2L, M2R, Lbf);
    monarch_transform3<true><<<dim3(256), dim3(512), 0, stream>>>(
        Q, Kv, M1L, M1R, M2L, M2R, Lbf, W, per, Qhat, Khat);
  } else {
    monarch_transform3<false><<<dim3(256), dim3(512), 0, stream>>>(
        Q, Kv, M1L, M1R, M2L, M2R, Lbf, W, per, Qhat, Khat);
  }

  score_gemm<<<dim3(2048), dim3(256), 0, stream>>>(Qhat, Khat, Out);
}

// Round 8
// 73.980 us; speedup vs baseline: 1.2812x; 1.1345x over previous
//
#include <hip/hip_runtime.h>
#include <hip/hip_bf16.h>
#include <math.h>

typedef __attribute__((ext_vector_type(8))) short short8;
typedef __attribute__((ext_vector_type(4))) short short4v;
typedef __attribute__((ext_vector_type(4))) float f32x4;
typedef __attribute__((ext_vector_type(4))) int int4v;

#define XP 1032

__device__ __forceinline__ short f2b(float v) {
  unsigned int u = __builtin_bit_cast(unsigned int, v);
  unsigned int r = (u + 0x7fffu + ((u >> 16) & 1u)) >> 16;
  return (short)(unsigned short)r;
}
__device__ __forceinline__ int ror10(int x, int k) {
  return ((x >> k) | (x << (10 - k))) & 1023;
}
__device__ __forceinline__ int swzj(int j) {
  return j ^ (((j >> 6) & 7) << 3);
}

// ------------------------------------------------------------------
// Kernel 0: convert the four monarch weight tensors fp32 -> bf16.
// ------------------------------------------------------------------
__global__ __launch_bounds__(256) void conv_lr(
    const float* __restrict__ M1L, const float* __restrict__ M1R,
    const float* __restrict__ M2L, const float* __restrict__ M2R,
    short* __restrict__ Lbf)
{
  int g = blockIdx.x * 256 + threadIdx.x;
  const float* srcs[4] = {M1L, M1R, M2L, M2R};
  #pragma unroll
  for (int t = 0; t < 4; ++t) {
    float4 v = *(const float4*)(srcs[t] + (size_t)g * 4);
    short4v o = { f2b(v.x), f2b(v.y), f2b(v.z), f2b(v.w) };
    *(short4v*)(Lbf + (size_t)t * 131072 + (size_t)g * 4) = o;
  }
}

// ------------------------------------------------------------------
// Kernel 1: monarch transform v3 (round-5, validated best).
// ------------------------------------------------------------------
template<bool USEBF>
__global__ __launch_bounds__(512) void monarch_transform3(
    const float* __restrict__ Q, const float* __restrict__ Kv,
    const float* __restrict__ M1L, const float* __restrict__ M1R,
    const float* __restrict__ M2L, const float* __restrict__ M2R,
    const short* __restrict__ Lbf,
    const float* __restrict__ W, const int* __restrict__ periods,
    short* __restrict__ Qh, short* __restrict__ Kh)
{
  const int bid = blockIdx.x;
  const int xcd = bid & 7;
  const int seq = bid >> 3;
  const int bh  = (xcd << 2) | (seq & 3);
  const int src = (seq >> 2) & 1;
  const int dc  = (seq >> 3) & 3;
  const int b   = bh >> 3;
  const int h   = bh & 7;

  __shared__ short raw[16 * XP];
  __shared__ short scr[16 * XP];

  const int tid  = threadIdx.x;
  const int lane = tid & 63;
  const int w    = tid >> 6;
  const int l15  = lane & 15;
  const int l4   = lane >> 4;

  float ws[4];
  {
    float w0 = W[b*4+0], w1 = W[b*4+1], w2 = W[b*4+2], w3 = W[b*4+3];
    float mx = fmaxf(fmaxf(w0, w1), fmaxf(w2, w3));
    float e0 = expf(w0-mx), e1 = expf(w1-mx), e2 = expf(w2-mx), e3 = expf(w3-mx);
    float inv = 1.0f / (e0+e1+e2+e3);
    ws[0]=e0*inv; ws[1]=e1*inv; ws[2]=e2*inv; ws[3]=e3*inv;
  }

  {
    const int dgrp = tid & 3;
    const int srow = tid >> 2;
    const float* xbase = (src ? Kv : Q)
        + (size_t)b*524288 + h*64 + dc*16 + dgrp*4;
    #pragma unroll
    for (int it = 0; it < 8; ++it) {
      int s = it*128 + srow;
      float4 v = *(const float4*)(xbase + (size_t)s * 512);
      raw[(dgrp*4+0)*XP + s] = f2b(v.x);
      raw[(dgrp*4+1)*XP + s] = f2b(v.y);
      raw[(dgrp*4+2)*XP + s] = f2b(v.z);
      raw[(dgrp*4+3)*XP + s] = f2b(v.w);
    }
  }
  __syncthreads();

  const short* LBs = Lbf + (size_t)(src ? 2 : 0) * 131072;
  const short* RBs = Lbf + (size_t)(src ? 3 : 1) * 131072;
  const float* LF  = src ? M2L : M1L;
  const float* RF  = src ? M2R : M1R;
  short* Out       = src ? Kh : Qh;

  for (int i = 0; i < 4; ++i) {
    const int p    = periods[i];
    const int lp   = 31 - __clz(p);
    const int kin  = 5 + lp;
    const int kf   = 5 - lp;
    const int str  = 1 << (10 - kin);
    const int mask = (1 << kin) - 1;
    const float scale = (src == 0) ? ws[i] : 1.0f;

    f32x4 acc[4][2];
    #pragma unroll
    for (int bi = 0; bi < 4; ++bi)
      #pragma unroll
      for (int rt = 0; rt < 2; ++rt) acc[bi][rt] = (f32x4){0.f,0.f,0.f,0.f};

    #pragma unroll
    for (int bi = 0; bi < 4; ++bi) {
      int bb = w*4 + bi;
      int j0 = bb*32 + l4*8;
      int s0 = (j0 >> kin) | ((j0 & mask) << (10 - kin));
      short8 a;
      #pragma unroll
      for (int e = 0; e < 8; ++e) a[e] = raw[l15*XP + s0 + e*str];
      #pragma unroll
      for (int rt = 0; rt < 2; ++rt) {
        int roff = ((i*32 + bb)*32 + rt*16 + l15)*32 + l4*8;
        short8 bf;
        if (USEBF) {
          bf = *(const short8*)(LBs + roff);
        } else {
          float4 u0 = *(const float4*)(LF + roff);
          float4 u1 = *(const float4*)(LF + roff + 4);
          bf[0]=f2b(u0.x); bf[1]=f2b(u0.y); bf[2]=f2b(u0.z); bf[3]=f2b(u0.w);
          bf[4]=f2b(u1.x); bf[5]=f2b(u1.y); bf[6]=f2b(u1.z); bf[7]=f2b(u1.w);
        }
        acc[bi][rt] = __builtin_amdgcn_mfma_f32_16x16x32_bf16(a, bf, acc[bi][rt], 0, 0, 0);
      }
    }

    #pragma unroll
    for (int rt = 0; rt < 2; ++rt)
      #pragma unroll
      for (int rr = 0; rr < 4; ++rr) {
        short4v v;
        #pragma unroll
        for (int bi = 0; bi < 4; ++bi) v[bi] = f2b(acc[bi][rt][rr]);
        int r  = rt*16 + l15;
        int d  = l4*4 + rr;
        int j2 = r*32 + w*4;
        *(short4v*)&scr[d*XP + swzj(j2)] = v;
      }
    __syncthreads();

    f32x4 ac2[4][2];
    #pragma unroll
    for (int bi = 0; bi < 4; ++bi)
      #pragma unroll
      for (int rt = 0; rt < 2; ++rt) ac2[bi][rt] = (f32x4){0.f,0.f,0.f,0.f};

    #pragma unroll
    for (int bi = 0; bi < 4; ++bi) {
      int bb = w*4 + bi;
      int j0 = bb*32 + l4*8;
      short8 a = *(const short8*)&scr[l15*XP + swzj(j0)];
      #pragma unroll
      for (int rt = 0; rt < 2; ++rt) {
        int roff = ((i*32 + bb)*32 + rt*16 + l15)*32 + l4*8;
        short8 bf;
        if (USEBF) {
          bf = *(const short8*)(RBs + roff);
        } else {
          float4 u0 = *(const float4*)(RF + roff);
          float4 u1 = *(const float4*)(RF + roff + 4);
          bf[0]=f2b(u0.x); bf[1]=f2b(u0.y); bf[2]=f2b(u0.z); bf[3]=f2b(u0.w);
          bf[4]=f2b(u1.x); bf[5]=f2b(u1.y); bf[6]=f2b(u1.z); bf[7]=f2b(u1.w);
        }
        ac2[bi][rt] = __builtin_amdgcn_mfma_f32_16x16x32_bf16(a, bf, ac2[bi][rt], 0, 0, 0);
      }
    }
    __syncthreads();

    #pragma unroll
    for (int bi = 0; bi < 4; ++bi)
      #pragma unroll
      for (int rt = 0; rt < 2; ++rt) {
        int m  = (w*4 + bi)*32 + rt*16 + l15;
        int jo = ror10(m, kf);
        int sw = (jo >> 5) & 3;
        unsigned int lo = (unsigned short)f2b(ac2[bi][rt][0] * scale)
                        | ((unsigned int)(unsigned short)f2b(ac2[bi][rt][1] * scale) << 16);
        unsigned int hi = (unsigned short)f2b(ac2[bi][rt][2] * scale)
                        | ((unsigned int)(unsigned short)f2b(ac2[bi][rt][3] * scale) << 16);
        uint2 pv; pv.x = lo; pv.y = hi;
        *(uint2*)&scr[jo*16 + ((l4 ^ sw) << 2)] = pv;
      }
    __syncthreads();

    {
      size_t obase = ((size_t)bh * 1024) * 256 + i*64 + dc*16;
      #pragma unroll
      for (int it2 = 0; it2 < 2; ++it2) {
        int jo = it2*512 + tid;
        int sw = (jo >> 5) & 3;
        uint2 g[4];
        #pragma unroll
        for (int gg = 0; gg < 4; ++gg)
          g[gg] = *(const uint2*)&scr[jo*16 + ((gg ^ sw) << 2)];
        int4v lo = {(int)g[0].x, (int)g[0].y, (int)g[1].x, (int)g[1].y};
        int4v hi = {(int)g[2].x, (int)g[2].y, (int)g[3].x, (int)g[3].y};
        short* op = Out + obase + (size_t)jo * 256;
        *(int4v*)(op)     = lo;
        *(int4v*)(op + 8) = hi;
      }
    }
    __syncthreads();
  }
}

// ------------------------------------------------------------------
// Kernel 2 (round-3 structure): batched GEMM out[s,l]=sum_k Q[s,k]K[l,k],
// K=256, 128x128 tiles, global_load_lds + XOR swizzle, XCD-affine.
// ONLY change vs round 5: plain f32x4 stores instead of nontemporal —
// let the 134MB output absorb into L3 and flush in the background.
// ------------------------------------------------------------------
__global__ __launch_bounds__(256) void score_gemm(
    const short* __restrict__ Qh, const short* __restrict__ Kh,
    float* __restrict__ Out)
{
  const int bid  = blockIdx.x;
  const int xcd  = bid & 7;
  const int seq  = bid >> 3;
  const int bh   = (xcd << 2) | (seq & 3);
  const int tile = seq >> 2;
  const int tm   = (tile >> 3) << 7;
  const int tn   = (tile & 7) << 7;

  __shared__ short As[128*64];
  __shared__ short Bs[128*64];

  const int tid  = threadIdx.x;
  const int lane = tid & 63;
  const int w    = tid >> 6;
  const int wm   = (w >> 1) << 6;
  const int wn   = (w & 1) << 6;
  const int l15  = lane & 15;
  const int l4   = lane >> 4;

  const short* Qb = Qh + (size_t)bh * (1024*256);
  const short* Kb = Kh + (size_t)bh * (1024*256);

  const int lrow = lane >> 3;
  const int kch  = (((lane & 7) ^ lrow) << 3);

  f32x4 acc[4][4];
  #pragma unroll
  for (int fm = 0; fm < 4; ++fm)
    #pragma unroll
    for (int fn = 0; fn < 4; ++fn) acc[fm][fn] = (f32x4){0.f,0.f,0.f,0.f};

  for (int kt = 0; kt < 4; ++kt) {
    #pragma unroll
    for (int q0 = 0; q0 < 4; ++q0) {
      int seg = w*4 + q0;
      int row = seg*8 + lrow;
      const short* srcA = Qb + (size_t)(tm + row)*256 + kt*64 + kch;
      const short* srcB = Kb + (size_t)(tn + row)*256 + kt*64 + kch;
      __builtin_amdgcn_global_load_lds(
          (const __attribute__((address_space(1))) unsigned int*)srcA,
          (__attribute__((address_space(3))) unsigned int*)&As[seg*512], 16, 0, 0);
      __builtin_amdgcn_global_load_lds(
          (const __attribute__((address_space(1))) unsigned int*)srcB,
          (__attribute__((address_space(3))) unsigned int*)&Bs[seg*512], 16, 0, 0);
    }
    __syncthreads();

    #pragma unroll
    for (int kk = 0; kk < 2; ++kk) {
      short8 af[4], bf[4];
      #pragma unroll
      for (int fm = 0; fm < 4; ++fm) {
        int row = wm + fm*16 + l15;
        int kl  = kk*32 + l4*8;
        af[fm] = *(const short8*)&As[row*64 + (kl ^ ((row & 7) << 3))];
      }
      #pragma unroll
      for (int fn = 0; fn < 4; ++fn) {
        int row = wn + fn*16 + l15;
        int kl  = kk*32 + l4*8;
        bf[fn] = *(const short8*)&Bs[row*64 + (kl ^ ((row & 7) << 3))];
      }
      // swapped operands: D rows = K-side (l), D cols = Q-side (s)
      #pragma unroll
      for (int fm = 0; fm < 4; ++fm)
        #pragma unroll
        for (int fn = 0; fn < 4; ++fn)
          acc[fm][fn] = __builtin_amdgcn_mfma_f32_16x16x32_bf16(bf[fn], af[fm], acc[fm][fn], 0, 0, 0);
    }
    __syncthreads();
  }

  // Epilogue: lane holds 4 consecutive l at fixed s -> plain float4 stores
  // (write-allocate into L2/L3; background flush overlaps later kernels).
  float* Ob = Out + ((size_t)bh << 20);
  #pragma unroll
  for (int fm = 0; fm < 4; ++fm) {
    int srow = tm + wm + fm*16 + l15;
    #pragma unroll
    for (int fn = 0; fn < 4; ++fn) {
      int lcol = tn + wn + fn*16 + l4*4;
      *(f32x4*)(Ob + ((size_t)srow << 10) + lcol) = acc[fm][fn];
    }
  }
}

extern "C" void kernel_launch(void* const* d_in, const int* in_sizes, int n_in,
                              void* d_out, int out_size, void* d_ws, size_t ws_size,
                              hipStream_t stream) {
  const float* Q   = (const float*)d_in[0];
  const float* Kv  = (const float*)d_in[1];
  const float* M1L = (const float*)d_in[2];
  const float* M1R = (const float*)d_in[3];
  const float* M2L = (const float*)d_in[4];
  const float* M2R = (const float*)d_in[5];
  const float* W   = (const float*)d_in[6];
  const int* per   = (const int*)d_in[7];
  float* Out       = (float*)d_out;

  const size_t qsz = (size_t)32 * 1024 * 256;
  short* Qhat = (short*)d_ws;
  short* Khat = Qhat + qsz;
  short* Lbf  = Khat + qsz;
  const size_t need = (qsz * 2 + (size_t)4 * 131072) * sizeof(short);
  const bool usebf = (ws_size >= need);

  if (usebf) {
    conv_lr<<<dim3(128), dim3(256), 0, stream>>>(M1L, M1R, M2L, M2R, Lbf);
    monarch_transform3<true><<<dim3(256), dim3(512), 0, stream>>>(
        Q, Kv, M1L, M1R, M2L, M2R, Lbf, W, per, Qhat, Khat);
  } else {
    monarch_transform3<false><<<dim3(256), dim3(512), 0, stream>>>(
        Q, Kv, M1L, M1R, M2L, M2R, Lbf, W, per, Qhat, Khat);
  }

  score_gemm<<<dim3(2048), dim3(256), 0, stream>>>(Qhat, Khat, Out);
}

// Round 9
// 69.147 us; speedup vs baseline: 1.3708x; 1.0699x over previous
//
#include <hip/hip_runtime.h>
#include <hip/hip_bf16.h>
#include <math.h>

typedef __attribute__((ext_vector_type(8))) short short8;
typedef __attribute__((ext_vector_type(4))) short short4v;
typedef __attribute__((ext_vector_type(4))) float f32x4;
typedef __attribute__((ext_vector_type(4))) int int4v;

#define XP 1032

__device__ __forceinline__ short f2b(float v) {
  unsigned int u = __builtin_bit_cast(unsigned int, v);
  unsigned int r = (u + 0x7fffu + ((u >> 16) & 1u)) >> 16;
  return (short)(unsigned short)r;
}
__device__ __forceinline__ int ror10(int x, int k) {
  return ((x >> k) | (x << (10 - k))) & 1023;
}
__device__ __forceinline__ int swzj(int j) {
  return j ^ (((j >> 6) & 7) << 3);
}

// ------------------------------------------------------------------
// Kernel 0: convert the four monarch weight tensors fp32 -> bf16.
// ------------------------------------------------------------------
__global__ __launch_bounds__(256) void conv_lr(
    const float* __restrict__ M1L, const float* __restrict__ M1R,
    const float* __restrict__ M2L, const float* __restrict__ M2R,
    short* __restrict__ Lbf)
{
  int g = blockIdx.x * 256 + threadIdx.x;
  const float* srcs[4] = {M1L, M1R, M2L, M2R};
  #pragma unroll
  for (int t = 0; t < 4; ++t) {
    float4 v = *(const float4*)(srcs[t] + (size_t)g * 4);
    short4v o = { f2b(v.x), f2b(v.y), f2b(v.z), f2b(v.w) };
    *(short4v*)(Lbf + (size_t)t * 131072 + (size_t)g * 4) = o;
  }
}

// ------------------------------------------------------------------
// Kernel 1: monarch transform v4. One block per (bh, src, dc, ip);
// ip = i-pair, 2 components per block. Grid 512 -> 2 blocks/CU.
// Qhat/Khat CHUNK layout: [bh][dc][i][s=1024][16 d]  (addr =
// (((bh*4+dc)*4+i)<<14) + s*16 + dl) -> phase-6 writes are 32KB
// CONTIGUOUS per (block, i): perfectly coalesced 32B/lane stores.
// XCD affinity: bid&7 = bh>>2 (matches score_gemm); ip-partner blocks
// (bid +/- 256) share the XCD so the duplicated X stage is an L2 hit.
// Arithmetic identical to validated v3.
// ------------------------------------------------------------------
template<bool USEBF>
__global__ __launch_bounds__(512) void monarch_transform4(
    const float* __restrict__ Q, const float* __restrict__ Kv,
    const float* __restrict__ M1L, const float* __restrict__ M1R,
    const float* __restrict__ M2L, const float* __restrict__ M2R,
    const short* __restrict__ Lbf,
    const float* __restrict__ W, const int* __restrict__ periods,
    short* __restrict__ Qh, short* __restrict__ Kh)
{
  const int bid = blockIdx.x;
  const int xcd = bid & 7;
  const int seq = bid >> 3;          // 0..63
  const int bh  = (xcd << 2) | (seq & 3);
  const int src = (seq >> 2) & 1;
  const int dc  = (seq >> 3) & 3;
  const int ip  = (seq >> 5) & 1;    // i-pair: {0,1} or {2,3}
  const int b   = bh >> 3;
  const int h   = bh & 7;

  __shared__ short raw[16 * XP];
  __shared__ short scr[16 * XP];

  const int tid  = threadIdx.x;
  const int lane = tid & 63;
  const int w    = tid >> 6;
  const int l15  = lane & 15;
  const int l4   = lane >> 4;

  float ws[4];
  {
    float w0 = W[b*4+0], w1 = W[b*4+1], w2 = W[b*4+2], w3 = W[b*4+3];
    float mx = fmaxf(fmaxf(w0, w1), fmaxf(w2, w3));
    float e0 = expf(w0-mx), e1 = expf(w1-mx), e2 = expf(w2-mx), e3 = expf(w3-mx);
    float inv = 1.0f / (e0+e1+e2+e3);
    ws[0]=e0*inv; ws[1]=e1*inv; ws[2]=e2*inv; ws[3]=e3*inv;
  }

  // ---- Stage raw X slice (bh, dc) as bf16 [16 d][1024 s] ----
  {
    const int dgrp = tid & 3;
    const int srow = tid >> 2;
    const float* xbase = (src ? Kv : Q)
        + (size_t)b*524288 + h*64 + dc*16 + dgrp*4;
    #pragma unroll
    for (int it = 0; it < 8; ++it) {
      int s = it*128 + srow;
      float4 v = *(const float4*)(xbase + (size_t)s * 512);
      raw[(dgrp*4+0)*XP + s] = f2b(v.x);
      raw[(dgrp*4+1)*XP + s] = f2b(v.y);
      raw[(dgrp*4+2)*XP + s] = f2b(v.z);
      raw[(dgrp*4+3)*XP + s] = f2b(v.w);
    }
  }
  __syncthreads();

  const short* LBs = Lbf + (size_t)(src ? 2 : 0) * 131072;
  const short* RBs = Lbf + (size_t)(src ? 3 : 1) * 131072;
  const float* LF  = src ? M2L : M1L;
  const float* RF  = src ? M2R : M1R;
  short* Out       = src ? Kh : Qh;

  for (int ii = 0; ii < 2; ++ii) {
    const int i    = ip*2 + ii;
    const int p    = periods[i];
    const int lp   = 31 - __clz(p);
    const int kin  = 5 + lp;
    const int kf   = 5 - lp;
    const int str  = 1 << (10 - kin);
    const int mask = (1 << kin) - 1;
    const float scale = (src == 0) ? ws[i] : 1.0f;

    // ---- Stage 1: t3 = blockdiag(L) * t2, A gathered from raw ----
    f32x4 acc[4][2];
    #pragma unroll
    for (int bi = 0; bi < 4; ++bi)
      #pragma unroll
      for (int rt = 0; rt < 2; ++rt) acc[bi][rt] = (f32x4){0.f,0.f,0.f,0.f};

    #pragma unroll
    for (int bi = 0; bi < 4; ++bi) {
      int bb = w*4 + bi;
      int j0 = bb*32 + l4*8;
      int s0 = (j0 >> kin) | ((j0 & mask) << (10 - kin));
      short8 a;
      #pragma unroll
      for (int e = 0; e < 8; ++e) a[e] = raw[l15*XP + s0 + e*str];
      #pragma unroll
      for (int rt = 0; rt < 2; ++rt) {
        int roff = ((i*32 + bb)*32 + rt*16 + l15)*32 + l4*8;
        short8 bf;
        if (USEBF) {
          bf = *(const short8*)(LBs + roff);
        } else {
          float4 u0 = *(const float4*)(LF + roff);
          float4 u1 = *(const float4*)(LF + roff + 4);
          bf[0]=f2b(u0.x); bf[1]=f2b(u0.y); bf[2]=f2b(u0.z); bf[3]=f2b(u0.w);
          bf[4]=f2b(u1.x); bf[5]=f2b(u1.y); bf[6]=f2b(u1.z); bf[7]=f2b(u1.w);
        }
        acc[bi][rt] = __builtin_amdgcn_mfma_f32_16x16x32_bf16(a, bf, acc[bi][rt], 0, 0, 0);
      }
    }

    // ---- t4 pack-write: t4[d][r*32+bb] = t3[bb*32+r] ----
    #pragma unroll
    for (int rt = 0; rt < 2; ++rt)
      #pragma unroll
      for (int rr = 0; rr < 4; ++rr) {
        short4v v;
        #pragma unroll
        for (int bi = 0; bi < 4; ++bi) v[bi] = f2b(acc[bi][rt][rr]);
        int r  = rt*16 + l15;
        int d  = l4*4 + rr;
        int j2 = r*32 + w*4;
        *(short4v*)&scr[d*XP + swzj(j2)] = v;
      }
    __syncthreads();

    // ---- Stage 2: t5 = blockdiag(R) * t4 ----
    f32x4 ac2[4][2];
    #pragma unroll
    for (int bi = 0; bi < 4; ++bi)
      #pragma unroll
      for (int rt = 0; rt < 2; ++rt) ac2[bi][rt] = (f32x4){0.f,0.f,0.f,0.f};

    #pragma unroll
    for (int bi = 0; bi < 4; ++bi) {
      int bb = w*4 + bi;
      int j0 = bb*32 + l4*8;
      short8 a = *(const short8*)&scr[l15*XP + swzj(j0)];
      #pragma unroll
      for (int rt = 0; rt < 2; ++rt) {
        int roff = ((i*32 + bb)*32 + rt*16 + l15)*32 + l4*8;
        short8 bf;
        if (USEBF) {
          bf = *(const short8*)(RBs + roff);
        } else {
          float4 u0 = *(const float4*)(RF + roff);
          float4 u1 = *(const float4*)(RF + roff + 4);
          bf[0]=f2b(u0.x); bf[1]=f2b(u0.y); bf[2]=f2b(u0.z); bf[3]=f2b(u0.w);
          bf[4]=f2b(u1.x); bf[5]=f2b(u1.y); bf[6]=f2b(u1.z); bf[7]=f2b(u1.w);
        }
        ac2[bi][rt] = __builtin_amdgcn_mfma_f32_16x16x32_bf16(a, bf, ac2[bi][rt], 0, 0, 0);
      }
    }
    __syncthreads();

    // ---- Phase 5: scatter t5 -> scr[jo][16 d] (b64, d-group swizzled) ----
    #pragma unroll
    for (int bi = 0; bi < 4; ++bi)
      #pragma unroll
      for (int rt = 0; rt < 2; ++rt) {
        int m  = (w*4 + bi)*32 + rt*16 + l15;
        int jo = ror10(m, kf);
        int sw = (jo >> 5) & 3;
        unsigned int lo = (unsigned short)f2b(ac2[bi][rt][0] * scale)
                        | ((unsigned int)(unsigned short)f2b(ac2[bi][rt][1] * scale) << 16);
        unsigned int hi = (unsigned short)f2b(ac2[bi][rt][2] * scale)
                        | ((unsigned int)(unsigned short)f2b(ac2[bi][rt][3] * scale) << 16);
        uint2 pv; pv.x = lo; pv.y = hi;
        *(uint2*)&scr[jo*16 + ((l4 ^ sw) << 2)] = pv;
      }
    __syncthreads();

    // ---- Phase 6: CONTIGUOUS chunk write [bh][dc][i][jo][16] ----
    {
      size_t obase = (size_t)((bh*4 + dc)*4 + i) << 14;   // *16384 shorts
      #pragma unroll
      for (int it2 = 0; it2 < 2; ++it2) {
        int jo = it2*512 + tid;
        int sw = (jo >> 5) & 3;
        uint2 g[4];
        #pragma unroll
        for (int gg = 0; gg < 4; ++gg)
          g[gg] = *(const uint2*)&scr[jo*16 + ((gg ^ sw) << 2)];
        int4v lo = {(int)g[0].x, (int)g[0].y, (int)g[1].x, (int)g[1].y};
        int4v hi = {(int)g[2].x, (int)g[2].y, (int)g[3].x, (int)g[3].y};
        short* op = Out + obase + (size_t)jo * 16;
        *(int4v*)(op)     = lo;
        *(int4v*)(op + 8) = hi;
      }
    }
    __syncthreads();
  }
}

// ------------------------------------------------------------------
// Kernel 2: batched GEMM (R8 structure, plain stores). Only change:
// global_load_lds SOURCE addresses decode the chunk layout
// [bh][dcp][i][s][16]; LDS layout, swizzle, MFMA, epilogue unchanged.
// ------------------------------------------------------------------
__global__ __launch_bounds__(256) void score_gemm(
    const short* __restrict__ Qh, const short* __restrict__ Kh,
    float* __restrict__ Out)
{
  const int bid  = blockIdx.x;
  const int xcd  = bid & 7;
  const int seq  = bid >> 3;
  const int bh   = (xcd << 2) | (seq & 3);
  const int tile = seq >> 2;
  const int tm   = (tile >> 3) << 7;
  const int tn   = (tile & 7) << 7;

  __shared__ short As[128*64];
  __shared__ short Bs[128*64];

  const int tid  = threadIdx.x;
  const int lane = tid & 63;
  const int w    = tid >> 6;
  const int wm   = (w >> 1) << 6;
  const int wn   = (w & 1) << 6;
  const int l15  = lane & 15;
  const int l4   = lane >> 4;

  const int lrow = lane >> 3;
  const int kch  = (((lane & 7) ^ lrow) << 3);   // swizzled k-offset (shorts)

  f32x4 acc[4][4];
  #pragma unroll
  for (int fm = 0; fm < 4; ++fm)
    #pragma unroll
    for (int fn = 0; fn < 4; ++fn) acc[fm][fn] = (f32x4){0.f,0.f,0.f,0.f};

  for (int kt = 0; kt < 4; ++kt) {
    // chunk-layout decode of the 16B piece at kd0 = kt*64 + kch
    const int kd0 = kt*64 + kch;
    const int ic  = kd0 >> 6;
    const int dcp = (kd0 >> 4) & 3;
    const int dl  = kd0 & 15;                    // 0 or 8
    const size_t cbase = (size_t)((bh*4 + dcp)*4 + ic) << 14;
    #pragma unroll
    for (int q0 = 0; q0 < 4; ++q0) {
      int seg = w*4 + q0;
      int row = seg*8 + lrow;
      const short* srcA = Qh + cbase + ((size_t)(tm + row) << 4) + dl;
      const short* srcB = Kh + cbase + ((size_t)(tn + row) << 4) + dl;
      __builtin_amdgcn_global_load_lds(
          (const __attribute__((address_space(1))) unsigned int*)srcA,
          (__attribute__((address_space(3))) unsigned int*)&As[seg*512], 16, 0, 0);
      __builtin_amdgcn_global_load_lds(
          (const __attribute__((address_space(1))) unsigned int*)srcB,
          (__attribute__((address_space(3))) unsigned int*)&Bs[seg*512], 16, 0, 0);
    }
    __syncthreads();

    #pragma unroll
    for (int kk = 0; kk < 2; ++kk) {
      short8 af[4], bf[4];
      #pragma unroll
      for (int fm = 0; fm < 4; ++fm) {
        int row = wm + fm*16 + l15;
        int kl  = kk*32 + l4*8;
        af[fm] = *(const short8*)&As[row*64 + (kl ^ ((row & 7) << 3))];
      }
      #pragma unroll
      for (int fn = 0; fn < 4; ++fn) {
        int row = wn + fn*16 + l15;
        int kl  = kk*32 + l4*8;
        bf[fn] = *(const short8*)&Bs[row*64 + (kl ^ ((row & 7) << 3))];
      }
      // swapped operands: D rows = K-side (l), D cols = Q-side (s)
      #pragma unroll
      for (int fm = 0; fm < 4; ++fm)
        #pragma unroll
        for (int fn = 0; fn < 4; ++fn)
          acc[fm][fn] = __builtin_amdgcn_mfma_f32_16x16x32_bf16(bf[fn], af[fm], acc[fm][fn], 0, 0, 0);
    }
    __syncthreads();
  }

  float* Ob = Out + ((size_t)bh << 20);
  #pragma unroll
  for (int fm = 0; fm < 4; ++fm) {
    int srow = tm + wm + fm*16 + l15;
    #pragma unroll
    for (int fn = 0; fn < 4; ++fn) {
      int lcol = tn + wn + fn*16 + l4*4;
      *(f32x4*)(Ob + ((size_t)srow << 10) + lcol) = acc[fm][fn];
    }
  }
}

extern "C" void kernel_launch(void* const* d_in, const int* in_sizes, int n_in,
                              void* d_out, int out_size, void* d_ws, size_t ws_size,
                              hipStream_t stream) {
  const float* Q   = (const float*)d_in[0];
  const float* Kv  = (const float*)d_in[1];
  const float* M1L = (const float*)d_in[2];
  const float* M1R = (const float*)d_in[3];
  const float* M2L = (const float*)d_in[4];
  const float* M2R = (const float*)d_in[5];
  const float* W   = (const float*)d_in[6];
  const int* per   = (const int*)d_in[7];
  float* Out       = (float*)d_out;

  const size_t qsz = (size_t)32 * 1024 * 256;
  short* Qhat = (short*)d_ws;
  short* Khat = Qhat + qsz;
  short* Lbf  = Khat + qsz;
  const size_t need = (qsz * 2 + (size_t)4 * 131072) * sizeof(short);
  const bool usebf = (ws_size >= need);

  if (usebf) {
    conv_lr<<<dim3(128), dim3(256), 0, stream>>>(M1L, M1R, M2L, M2R, Lbf);
    monarch_transform4<true><<<dim3(512), dim3(512), 0, stream>>>(
        Q, Kv, M1L, M1R, M2L, M2R, Lbf, W, per, Qhat, Khat);
  } else {
    monarch_transform4<false><<<dim3(512), dim3(512), 0, stream>>>(
        Q, Kv, M1L, M1R, M2L, M2R, Lbf, W, per, Qhat, Khat);
  }

  score_gemm<<<dim3(2048), dim3(256), 0, stream>>>(Qhat, Khat, Out);
}

// Round 10
// 68.916 us; speedup vs baseline: 1.3754x; 1.0034x over previous
//
#include <hip/hip_runtime.h>
#include <hip/hip_bf16.h>
#include <math.h>

typedef __attribute__((ext_vector_type(8))) short short8;
typedef __attribute__((ext_vector_type(4))) short short4v;
typedef __attribute__((ext_vector_type(4))) float f32x4;
typedef __attribute__((ext_vector_type(4))) int int4v;

#define XP 1032

__device__ __forceinline__ short f2b(float v) {
  unsigned int u = __builtin_bit_cast(unsigned int, v);
  unsigned int r = (u + 0x7fffu + ((u >> 16) & 1u)) >> 16;
  return (short)(unsigned short)r;
}
__device__ __forceinline__ int ror10(int x, int k) {
  return ((x >> k) | (x << (10 - k))) & 1023;
}
__device__ __forceinline__ int swzj(int j) {
  return j ^ (((j >> 6) & 7) << 3);
}
// raw-buffer column swizzle: spreads bank index over shorts-bits 1-4 using
// both the row (d) and the s-high bits (where the l4-group offset lives).
// Bijective in s for fixed d (only bits 1-4 are XORed; s>>6 untouched).
__device__ __forceinline__ int cswz(int s, int d) {
  return s ^ (((d ^ (s >> 6)) & 15) << 1);
}

// ------------------------------------------------------------------
// Kernel 0: convert the four monarch weight tensors fp32 -> bf16.
// ------------------------------------------------------------------
__global__ __launch_bounds__(256) void conv_lr(
    const float* __restrict__ M1L, const float* __restrict__ M1R,
    const float* __restrict__ M2L, const float* __restrict__ M2R,
    short* __restrict__ Lbf)
{
  int g = blockIdx.x * 256 + threadIdx.x;
  const float* srcs[4] = {M1L, M1R, M2L, M2R};
  #pragma unroll
  for (int t = 0; t < 4; ++t) {
    float4 v = *(const float4*)(srcs[t] + (size_t)g * 4);
    short4v o = { f2b(v.x), f2b(v.y), f2b(v.z), f2b(v.w) };
    *(short4v*)(Lbf + (size_t)t * 131072 + (size_t)g * 4) = o;
  }
}

// ------------------------------------------------------------------
// Kernel 1: monarch transform v5 = v4 + bank-conflict-free raw buffer
// (pitch 1024 + cswz column swizzle on both write and read sides).
// One block per (bh, src, dc, ip); chunk output layout
// [bh][dc][i][s][16] (validated R9). Arithmetic identical to v4.
// ------------------------------------------------------------------
template<bool USEBF>
__global__ __launch_bounds__(512) void monarch_transform5(
    const float* __restrict__ Q, const float* __restrict__ Kv,
    const float* __restrict__ M1L, const float* __restrict__ M1R,
    const float* __restrict__ M2L, const float* __restrict__ M2R,
    const short* __restrict__ Lbf,
    const float* __restrict__ W, const int* __restrict__ periods,
    short* __restrict__ Qh, short* __restrict__ Kh)
{
  const int bid = blockIdx.x;
  const int xcd = bid & 7;
  const int seq = bid >> 3;          // 0..63
  const int bh  = (xcd << 2) | (seq & 3);
  const int src = (seq >> 2) & 1;
  const int dc  = (seq >> 3) & 3;
  const int ip  = (seq >> 5) & 1;    // i-pair: {0,1} or {2,3}
  const int b   = bh >> 3;
  const int h   = bh & 7;

  __shared__ short raw[16 * 1024];   // 32 KB, swizzled columns
  __shared__ short scr[16 * XP];     // 33 KB (t4 scratch / out transpose)

  const int tid  = threadIdx.x;
  const int lane = tid & 63;
  const int w    = tid >> 6;
  const int l15  = lane & 15;
  const int l4   = lane >> 4;

  float ws[4];
  {
    float w0 = W[b*4+0], w1 = W[b*4+1], w2 = W[b*4+2], w3 = W[b*4+3];
    float mx = fmaxf(fmaxf(w0, w1), fmaxf(w2, w3));
    float e0 = expf(w0-mx), e1 = expf(w1-mx), e2 = expf(w2-mx), e3 = expf(w3-mx);
    float inv = 1.0f / (e0+e1+e2+e3);
    ws[0]=e0*inv; ws[1]=e1*inv; ws[2]=e2*inv; ws[3]=e3*inv;
  }

  // ---- Stage raw X slice (bh, dc) as bf16 [16 d][1024 s], swizzled ----
  {
    const int dgrp = tid & 3;
    const int srow = tid >> 2;
    const float* xbase = (src ? Kv : Q)
        + (size_t)b*524288 + h*64 + dc*16 + dgrp*4;
    #pragma unroll
    for (int it = 0; it < 8; ++it) {
      int s = it*128 + srow;
      float4 v = *(const float4*)(xbase + (size_t)s * 512);
      raw[(dgrp*4+0)*1024 + cswz(s, dgrp*4+0)] = f2b(v.x);
      raw[(dgrp*4+1)*1024 + cswz(s, dgrp*4+1)] = f2b(v.y);
      raw[(dgrp*4+2)*1024 + cswz(s, dgrp*4+2)] = f2b(v.z);
      raw[(dgrp*4+3)*1024 + cswz(s, dgrp*4+3)] = f2b(v.w);
    }
  }
  __syncthreads();

  const short* LBs = Lbf + (size_t)(src ? 2 : 0) * 131072;
  const short* RBs = Lbf + (size_t)(src ? 3 : 1) * 131072;
  const float* LF  = src ? M2L : M1L;
  const float* RF  = src ? M2R : M1R;
  short* Out       = src ? Kh : Qh;

  for (int ii = 0; ii < 2; ++ii) {
    const int i    = ip*2 + ii;
    const int p    = periods[i];
    const int lp   = 31 - __clz(p);
    const int kin  = 5 + lp;
    const int kf   = 5 - lp;
    const int str  = 1 << (10 - kin);
    const int mask = (1 << kin) - 1;
    const float scale = (src == 0) ? ws[i] : 1.0f;

    // ---- Stage 1: t3 = blockdiag(L) * t2, A gathered from raw ----
    f32x4 acc[4][2];
    #pragma unroll
    for (int bi = 0; bi < 4; ++bi)
      #pragma unroll
      for (int rt = 0; rt < 2; ++rt) acc[bi][rt] = (f32x4){0.f,0.f,0.f,0.f};

    #pragma unroll
    for (int bi = 0; bi < 4; ++bi) {
      int bb = w*4 + bi;
      int j0 = bb*32 + l4*8;
      int s0 = (j0 >> kin) | ((j0 & mask) << (10 - kin));
      short8 a;
      #pragma unroll
      for (int e = 0; e < 8; ++e) {
        int s = s0 + e*str;
        a[e] = raw[l15*1024 + cswz(s, l15)];
      }
      #pragma unroll
      for (int rt = 0; rt < 2; ++rt) {
        int roff = ((i*32 + bb)*32 + rt*16 + l15)*32 + l4*8;
        short8 bf;
        if (USEBF) {
          bf = *(const short8*)(LBs + roff);
        } else {
          float4 u0 = *(const float4*)(LF + roff);
          float4 u1 = *(const float4*)(LF + roff + 4);
          bf[0]=f2b(u0.x); bf[1]=f2b(u0.y); bf[2]=f2b(u0.z); bf[3]=f2b(u0.w);
          bf[4]=f2b(u1.x); bf[5]=f2b(u1.y); bf[6]=f2b(u1.z); bf[7]=f2b(u1.w);
        }
        acc[bi][rt] = __builtin_amdgcn_mfma_f32_16x16x32_bf16(a, bf, acc[bi][rt], 0, 0, 0);
      }
    }

    // ---- t4 pack-write: t4[d][r*32+bb] = t3[bb*32+r] ----
    #pragma unroll
    for (int rt = 0; rt < 2; ++rt)
      #pragma unroll
      for (int rr = 0; rr < 4; ++rr) {
        short4v v;
        #pragma unroll
        for (int bi = 0; bi < 4; ++bi) v[bi] = f2b(acc[bi][rt][rr]);
        int r  = rt*16 + l15;
        int d  = l4*4 + rr;
        int j2 = r*32 + w*4;
        *(short4v*)&scr[d*XP + swzj(j2)] = v;
      }
    __syncthreads();

    // ---- Stage 2: t5 = blockdiag(R) * t4 ----
    f32x4 ac2[4][2];
    #pragma unroll
    for (int bi = 0; bi < 4; ++bi)
      #pragma unroll
      for (int rt = 0; rt < 2; ++rt) ac2[bi][rt] = (f32x4){0.f,0.f,0.f,0.f};

    #pragma unroll
    for (int bi = 0; bi < 4; ++bi) {
      int bb = w*4 + bi;
      int j0 = bb*32 + l4*8;
      short8 a = *(const short8*)&scr[l15*XP + swzj(j0)];
      #pragma unroll
      for (int rt = 0; rt < 2; ++rt) {
        int roff = ((i*32 + bb)*32 + rt*16 + l15)*32 + l4*8;
        short8 bf;
        if (USEBF) {
          bf = *(const short8*)(RBs + roff);
        } else {
          float4 u0 = *(const float4*)(RF + roff);
          float4 u1 = *(const float4*)(RF + roff + 4);
          bf[0]=f2b(u0.x); bf[1]=f2b(u0.y); bf[2]=f2b(u0.z); bf[3]=f2b(u0.w);
          bf[4]=f2b(u1.x); bf[5]=f2b(u1.y); bf[6]=f2b(u1.z); bf[7]=f2b(u1.w);
        }
        ac2[bi][rt] = __builtin_amdgcn_mfma_f32_16x16x32_bf16(a, bf, ac2[bi][rt], 0, 0, 0);
      }
    }
    __syncthreads();

    // ---- Phase 5: scatter t5 -> scr[jo][16 d] (b64, d-group swizzled) ----
    #pragma unroll
    for (int bi = 0; bi < 4; ++bi)
      #pragma unroll
      for (int rt = 0; rt < 2; ++rt) {
        int m  = (w*4 + bi)*32 + rt*16 + l15;
        int jo = ror10(m, kf);
        int sw = (jo >> 5) & 3;
        unsigned int lo = (unsigned short)f2b(ac2[bi][rt][0] * scale)
                        | ((unsigned int)(unsigned short)f2b(ac2[bi][rt][1] * scale) << 16);
        unsigned int hi = (unsigned short)f2b(ac2[bi][rt][2] * scale)
                        | ((unsigned int)(unsigned short)f2b(ac2[bi][rt][3] * scale) << 16);
        uint2 pv; pv.x = lo; pv.y = hi;
        *(uint2*)&scr[jo*16 + ((l4 ^ sw) << 2)] = pv;
      }
    __syncthreads();

    // ---- Phase 6: CONTIGUOUS chunk write [bh][dc][i][jo][16] ----
    {
      size_t obase = (size_t)((bh*4 + dc)*4 + i) << 14;   // *16384 shorts
      #pragma unroll
      for (int it2 = 0; it2 < 2; ++it2) {
        int jo = it2*512 + tid;
        int sw = (jo >> 5) & 3;
        uint2 g[4];
        #pragma unroll
        for (int gg = 0; gg < 4; ++gg)
          g[gg] = *(const uint2*)&scr[jo*16 + ((gg ^ sw) << 2)];
        int4v lo = {(int)g[0].x, (int)g[0].y, (int)g[1].x, (int)g[1].y};
        int4v hi = {(int)g[2].x, (int)g[2].y, (int)g[3].x, (int)g[3].y};
        short* op = Out + obase + (size_t)jo * 16;
        *(int4v*)(op)     = lo;
        *(int4v*)(op + 8) = hi;
      }
    }
    __syncthreads();
  }
}

// ------------------------------------------------------------------
// Kernel 2: batched GEMM (validated R9): chunk-layout sources,
// global_load_lds + XOR swizzle, XCD-affine, plain f32x4 stores.
// ------------------------------------------------------------------
__global__ __launch_bounds__(256) void score_gemm(
    const short* __restrict__ Qh, const short* __restrict__ Kh,
    float* __restrict__ Out)
{
  const int bid  = blockIdx.x;
  const int xcd  = bid & 7;
  const int seq  = bid >> 3;
  const int bh   = (xcd << 2) | (seq & 3);
  const int tile = seq >> 2;
  const int tm   = (tile >> 3) << 7;
  const int tn   = (tile & 7) << 7;

  __shared__ short As[128*64];
  __shared__ short Bs[128*64];

  const int tid  = threadIdx.x;
  const int lane = tid & 63;
  const int w    = tid >> 6;
  const int wm   = (w >> 1) << 6;
  const int wn   = (w & 1) << 6;
  const int l15  = lane & 15;
  const int l4   = lane >> 4;

  const int lrow = lane >> 3;
  const int kch  = (((lane & 7) ^ lrow) << 3);   // swizzled k-offset (shorts)

  f32x4 acc[4][4];
  #pragma unroll
  for (int fm = 0; fm < 4; ++fm)
    #pragma unroll
    for (int fn = 0; fn < 4; ++fn) acc[fm][fn] = (f32x4){0.f,0.f,0.f,0.f};

  for (int kt = 0; kt < 4; ++kt) {
    const int kd0 = kt*64 + kch;
    const int ic  = kd0 >> 6;
    const int dcp = (kd0 >> 4) & 3;
    const int dl  = kd0 & 15;
    const size_t cbase = (size_t)((bh*4 + dcp)*4 + ic) << 14;
    #pragma unroll
    for (int q0 = 0; q0 < 4; ++q0) {
      int seg = w*4 + q0;
      int row = seg*8 + lrow;
      const short* srcA = Qh + cbase + ((size_t)(tm + row) << 4) + dl;
      const short* srcB = Kh + cbase + ((size_t)(tn + row) << 4) + dl;
      __builtin_amdgcn_global_load_lds(
          (const __attribute__((address_space(1))) unsigned int*)srcA,
          (__attribute__((address_space(3))) unsigned int*)&As[seg*512], 16, 0, 0);
      __builtin_amdgcn_global_load_lds(
          (const __attribute__((address_space(1))) unsigned int*)srcB,
          (__attribute__((address_space(3))) unsigned int*)&Bs[seg*512], 16, 0, 0);
    }
    __syncthreads();

    #pragma unroll
    for (int kk = 0; kk < 2; ++kk) {
      short8 af[4], bf[4];
      #pragma unroll
      for (int fm = 0; fm < 4; ++fm) {
        int row = wm + fm*16 + l15;
        int kl  = kk*32 + l4*8;
        af[fm] = *(const short8*)&As[row*64 + (kl ^ ((row & 7) << 3))];
      }
      #pragma unroll
      for (int fn = 0; fn < 4; ++fn) {
        int row = wn + fn*16 + l15;
        int kl  = kk*32 + l4*8;
        bf[fn] = *(const short8*)&Bs[row*64 + (kl ^ ((row & 7) << 3))];
      }
      #pragma unroll
      for (int fm = 0; fm < 4; ++fm)
        #pragma unroll
        for (int fn = 0; fn < 4; ++fn)
          acc[fm][fn] = __builtin_amdgcn_mfma_f32_16x16x32_bf16(bf[fn], af[fm], acc[fm][fn], 0, 0, 0);
    }
    __syncthreads();
  }

  float* Ob = Out + ((size_t)bh << 20);
  #pragma unroll
  for (int fm = 0; fm < 4; ++fm) {
    int srow = tm + wm + fm*16 + l15;
    #pragma unroll
    for (int fn = 0; fn < 4; ++fn) {
      int lcol = tn + wn + fn*16 + l4*4;
      *(f32x4*)(Ob + ((size_t)srow << 10) + lcol) = acc[fm][fn];
    }
  }
}

extern "C" void kernel_launch(void* const* d_in, const int* in_sizes, int n_in,
                              void* d_out, int out_size, void* d_ws, size_t ws_size,
                              hipStream_t stream) {
  const float* Q   = (const float*)d_in[0];
  const float* Kv  = (const float*)d_in[1];
  const float* M1L = (const float*)d_in[2];
  const float* M1R = (const float*)d_in[3];
  const float* M2L = (const float*)d_in[4];
  const float* M2R = (const float*)d_in[5];
  const float* W   = (const float*)d_in[6];
  const int* per   = (const int*)d_in[7];
  float* Out       = (float*)d_out;

  const size_t qsz = (size_t)32 * 1024 * 256;
  short* Qhat = (short*)d_ws;
  short* Khat = Qhat + qsz;
  short* Lbf  = Khat + qsz;
  const size_t need = (qsz * 2 + (size_t)4 * 131072) * sizeof(short);
  const bool usebf = (ws_size >= need);

  if (usebf) {
    conv_lr<<<dim3(128), dim3(256), 0, stream>>>(M1L, M1R, M2L, M2R, Lbf);
    monarch_transform5<true><<<dim3(512), dim3(512), 0, stream>>>(
        Q, Kv, M1L, M1R, M2L, M2R, Lbf, W, per, Qhat, Khat);
  } else {
    monarch_transform5<false><<<dim3(512), dim3(512), 0, stream>>>(
        Q, Kv, M1L, M1R, M2L, M2R, Lbf, W, per, Qhat, Khat);
  }

  score_gemm<<<dim3(2048), dim3(256), 0, stream>>>(Qhat, Khat, Out);
}